// Round 1
// baseline (115.801 us; speedup 1.0000x reference)
//
#include <hip/hip_runtime.h>
#include <hip/hip_bf16.h>

// Ensemble SRN: 8 sub-models (2x2x2 octants), MLP 3->128->128->128->1, ReLU.
// R3: swapped-operand MFMA (D = h^T) -> packed b64 epilogue writes;
//     layer3 fused into gemm2 accumulator (fp32, no h2 LDS round-trip);
//     prep writes perm-ordered float4 {xn0,xn1,xn2,pid} -> coalesced tile loads.
// ws layout: [0,64)      cursors[8]
//            [256, +8*SEGCAP*16)  xperm f32x4 segments (3.3 MB)
//            [.., +256KB) Wt1 bf16 [8][128][128]  (transposed: [n][k])
//            [.., +256KB) Wt2 bf16 [8][128][128]

#define HDIM 128
#define LDSH 136      // padded LDS stride (bf16): 272B rows
#define TILE 64
#define NMODEL 8
#define TILES_X 272
#define SEGCAP 20480  // per-model segment capacity (mean 16384, +34 sigma)

typedef __bf16 bf16x8 __attribute__((ext_vector_type(8)));
typedef __bf16 bf16x4 __attribute__((ext_vector_type(4)));
typedef float  f32x4  __attribute__((ext_vector_type(4)));

__device__ __forceinline__ int model_of(float x0, float x1, float x2) {
  // match reference: u=(x+1)/(2+1e-6); cell=int(u_flipped*2); idx=c0+2c1+4c2
  const float den = 2.000001f;
  float u0 = (x0 + 1.0f) / den;
  float u1 = (x1 + 1.0f) / den;
  float u2 = (x2 + 1.0f) / den;
  int c0 = (int)(u2 * 2.0f);
  int c1 = (int)(u1 * 2.0f);
  int c2 = (int)(u0 * 2.0f);
  return c0 + (c1 << 1) + (c2 << 2);
}

// ---------- fused: weight transpose (blocks 0..63) + point scatter (rest) ----------
__global__ __launch_bounds__(256)
void srn_prep_scatter(const float* __restrict__ W1, const float* __restrict__ W2,
                      const float* __restrict__ x,
                      const float* __restrict__ mins, const float* __restrict__ maxs,
                      __bf16* __restrict__ Wt1, __bf16* __restrict__ Wt2,
                      int* __restrict__ cursors, f32x4* __restrict__ xperm, int N)
{
  const int b = blockIdx.x;
  const int tid = threadIdx.x;

  if (b < 64) {
    // ---- transpose one 64x64 fp32 tile -> bf16 Wt[n][k] ----
    __shared__ float lds[64][65];   // +1 pad: column reads conflict-free
    const int m   = b >> 3;
    const int r2  = b & 7;
    const int mat = r2 >> 2;
    const int ti  = (r2 >> 1) & 1;  // k-tile
    const int tj  = r2 & 1;         // n-tile
    const float* src = (mat ? W2 : W1) + m * HDIM * HDIM;
    __bf16*      dst = (mat ? Wt2 : Wt1) + m * HDIM * HDIM;
    #pragma unroll
    for (int it = 0; it < 16; ++it) {
      const int rr = (tid >> 6) + it * 4, cc = tid & 63;
      lds[rr][cc] = src[(ti * 64 + rr) * HDIM + tj * 64 + cc];   // coalesced 256B rows
    }
    __syncthreads();
    #pragma unroll
    for (int it = 0; it < 16; ++it) {
      const int nn = (tid >> 6) + it * 4, kk = tid & 63;
      dst[(tj * 64 + nn) * HDIM + ti * 64 + kk] = (__bf16)lds[kk][nn];  // coalesced 128B rows
    }
  } else {
    // ---- scatter 1024 points/block: normalized coords + pid into segments ----
    __shared__ int lc[NMODEL], lb[NMODEL];
    __shared__ float mnS[NMODEL * 3], ivS[NMODEL * 3];
    if (tid < NMODEL) lc[tid] = 0;
    if (tid < NMODEL * 3) { mnS[tid] = mins[tid]; ivS[tid] = 2.0f / (maxs[tid] - mins[tid]); }
    __syncthreads();
    const int base = (b - 64) * 1024;
    int ids[4], rs[4];
    float px[4][3];
    #pragma unroll
    for (int it = 0; it < 4; ++it) {
      const int i = base + it * 256 + tid;
      if (i < N) {
        float x0 = x[3*i], x1 = x[3*i+1], x2 = x[3*i+2];
        px[it][0] = x0; px[it][1] = x1; px[it][2] = x2;
        ids[it] = model_of(x0, x1, x2);
        rs[it] = atomicAdd(&lc[ids[it]], 1);
      } else ids[it] = -1;
    }
    __syncthreads();
    if (tid < NMODEL) lb[tid] = lc[tid] ? atomicAdd(&cursors[tid], lc[tid]) : 0;
    __syncthreads();
    #pragma unroll
    for (int it = 0; it < 4; ++it) {
      if (ids[it] >= 0) {
        const int id = ids[it];
        const int i = base + it * 256 + tid;
        const int slot = lb[id] + rs[it];
        if (slot < SEGCAP) {
          f32x4 v;
          v[0] = -1.0f + (px[it][0] - mnS[3*id  ]) * ivS[3*id  ];
          v[1] = -1.0f + (px[it][1] - mnS[3*id+1]) * ivS[3*id+1];
          v[2] = -1.0f + (px[it][2] - mnS[3*id+2]) * ivS[3*id+2];
          v[3] = __int_as_float(i);
          xperm[(size_t)id * SEGCAP + slot] = v;
        }
      }
    }
  }
}

// ---------- main: per-model tiled MLP ----------
// Swapped-operand MFMA: D[n][p] = sum_k Wt[n][k]*h[p][k]  (= h2^T)
//   A-frag = Wt rows (lane l16 = n-offset), B-frag = h rows (lane l16 = p-offset)
//   C/D: col(=p-offset) = l16, row(=n-offset) = quad*4 + reg  -> 4 consecutive n per reg group
__global__ __launch_bounds__(256, 4)
void srn_main(const float* __restrict__ W0, const float* __restrict__ b0,
              const float* __restrict__ b1, const float* __restrict__ b2,
              const float* __restrict__ W3, const float* __restrict__ b3,
              const __bf16* __restrict__ Wt1, const __bf16* __restrict__ Wt2,
              const int* __restrict__ cursors, const f32x4* __restrict__ xperm,
              float* __restrict__ out, int N)
{
  __shared__ __align__(16) __bf16 hA[TILE * LDSH];
  __shared__ __align__(16) __bf16 hB[TILE * LDSH];
  __shared__ f32x4 xs4[TILE];
  __shared__ float w0s[3 * HDIM];
  __shared__ float b0s[HDIM];
  __shared__ float part[4][TILE];

  const int m = blockIdx.y;
  const int tid = threadIdx.x;
  const int lane = tid & 63;
  const int wave = tid >> 6;
  const int l16  = lane & 15;
  const int quad = lane >> 4;
  const int n0   = wave * 32;

  if (tid < HDIM) {
    w0s[tid]          = W0[m * 3 * HDIM + tid];
    w0s[HDIM + tid]   = W0[m * 3 * HDIM + HDIM + tid];
    w0s[2*HDIM + tid] = W0[m * 3 * HDIM + 2 * HDIM + tid];
    b0s[tid] = b0[m * HDIM + tid];
  }
  // per-lane bias/w3 registers: fixed n-indices for all tiles
  f32x4 b1r[2], b2r[2], w3r[2];
  #pragma unroll
  for (int nt = 0; nt < 2; ++nt) {
    const int nb = m * HDIM + n0 + nt * 16 + quad * 4;
    b1r[nt] = *(const f32x4*)(b1 + nb);
    b2r[nt] = *(const f32x4*)(b2 + nb);
    w3r[nt] = *(const f32x4*)(W3 + nb);
  }
  const int cnt = cursors[m];
  const float b3v = b3[m];
  const __bf16* Wt1m = Wt1 + m * HDIM * HDIM;
  const __bf16* Wt2m = Wt2 + m * HDIM * HDIM;
  const f32x4* xp = xperm + (size_t)m * SEGCAP;
  __syncthreads();

  for (int tile = blockIdx.x; tile * TILE < cnt; tile += gridDim.x) {
    const int base = tile * TILE;
    const int npts = min(TILE, cnt - base);

    if (tid < TILE) {
      f32x4 v;
      if (tid < npts) v = xp[base + tid];               // one coalesced 16B load
      else { v[0] = 0.0f; v[1] = 0.0f; v[2] = 0.0f; v[3] = __int_as_float(-1); }
      xs4[tid] = v;
    }
    __syncthreads();   // A: xs4 ready

    // ---- layer 0: fp32 VALU, K=3 -> hA bf16 (b128 writes, conflict-free) ----
    {
      const int p  = lane;
      const int j0 = wave * 32;
      const f32x4 xv = xs4[p];
      #pragma unroll
      for (int jj = 0; jj < 32; jj += 8) {
        bf16x8 pk;
        #pragma unroll
        for (int u8 = 0; u8 < 8; u8 += 4) {
          const int j = j0 + jj + u8;
          f32x4 wa = *(const f32x4*)&w0s[j];
          f32x4 wb = *(const f32x4*)&w0s[HDIM + j];
          f32x4 wc = *(const f32x4*)&w0s[2*HDIM + j];
          f32x4 bb = *(const f32x4*)&b0s[j];
          #pragma unroll
          for (int u = 0; u < 4; ++u) {
            float v = fmaf(xv[0], wa[u], fmaf(xv[1], wb[u], fmaf(xv[2], wc[u], bb[u])));
            pk[u8 + u] = (__bf16)fmaxf(v, 0.0f);
          }
        }
        *(bf16x8*)(hA + p * LDSH + j0 + jj) = pk;
      }
    }
    __syncthreads();   // B: hA ready

    // ---- layer 1: hB^T tiles = relu(Wt1 . hA^T + b1), packed b64 writes ----
    {
      f32x4 acc[2][4] = {};
      #pragma unroll
      for (int kk = 0; kk < 4; ++kk) {
        const int kOff = kk * 32 + quad * 8;
        bf16x8 a0 = *(const bf16x8*)(Wt1m + (n0 + l16) * HDIM + kOff);
        bf16x8 a1 = *(const bf16x8*)(Wt1m + (n0 + 16 + l16) * HDIM + kOff);
        #pragma unroll
        for (int pt = 0; pt < 4; ++pt) {
          bf16x8 bv = *(const bf16x8*)(hA + (pt * 16 + l16) * LDSH + kOff);
          acc[0][pt] = __builtin_amdgcn_mfma_f32_16x16x32_bf16(a0, bv, acc[0][pt], 0, 0, 0);
          acc[1][pt] = __builtin_amdgcn_mfma_f32_16x16x32_bf16(a1, bv, acc[1][pt], 0, 0, 0);
        }
      }
      #pragma unroll
      for (int nt = 0; nt < 2; ++nt) {
        #pragma unroll
        for (int pt = 0; pt < 4; ++pt) {
          bf16x4 pk;
          #pragma unroll
          for (int i = 0; i < 4; ++i)
            pk[i] = (__bf16)fmaxf(acc[nt][pt][i] + b1r[nt][i], 0.0f);
          *(bf16x4*)(hB + (pt * 16 + l16) * LDSH + n0 + nt * 16 + quad * 4) = pk;
        }
      }
    }
    __syncthreads();   // C: hB ready

    // ---- layer 2 + layer 3 fused: y_p += relu(acc + b2[n]) * w3[n], fp32 ----
    {
      f32x4 acc[2][4] = {};
      #pragma unroll
      for (int kk = 0; kk < 4; ++kk) {
        const int kOff = kk * 32 + quad * 8;
        bf16x8 a0 = *(const bf16x8*)(Wt2m + (n0 + l16) * HDIM + kOff);
        bf16x8 a1 = *(const bf16x8*)(Wt2m + (n0 + 16 + l16) * HDIM + kOff);
        #pragma unroll
        for (int pt = 0; pt < 4; ++pt) {
          bf16x8 bv = *(const bf16x8*)(hB + (pt * 16 + l16) * LDSH + kOff);
          acc[0][pt] = __builtin_amdgcn_mfma_f32_16x16x32_bf16(a0, bv, acc[0][pt], 0, 0, 0);
          acc[1][pt] = __builtin_amdgcn_mfma_f32_16x16x32_bf16(a1, bv, acc[1][pt], 0, 0, 0);
        }
      }
      #pragma unroll
      for (int pt = 0; pt < 4; ++pt) {
        float s = 0.0f;
        #pragma unroll
        for (int nt = 0; nt < 2; ++nt)
          #pragma unroll
          for (int i = 0; i < 4; ++i)
            s = fmaf(fmaxf(acc[nt][pt][i] + b2r[nt][i], 0.0f), w3r[nt][i], s);
        s += __shfl_xor(s, 16);   // reduce across quad bit0
        s += __shfl_xor(s, 32);   // reduce across quad bit1
        if (quad == 0) part[wave][pt * 16 + l16] = s;
      }
    }
    __syncthreads();   // D: part ready

    // ---- output (wave0 only; no barrier before next xs-load: same wave) ----
    if (tid < TILE) {
      const float y = part[0][tid] + part[1][tid] + part[2][tid] + part[3][tid] + b3v;
      const int p = __float_as_int(xs4[tid][3]);
      if (p >= 0) out[p] = y;
    }
  }
}

extern "C" void kernel_launch(void* const* d_in, const int* in_sizes, int n_in,
                              void* d_out, int out_size, void* d_ws, size_t ws_size,
                              hipStream_t stream)
{
  const float* x    = (const float*)d_in[0];
  const float* W0   = (const float*)d_in[1];
  const float* b0   = (const float*)d_in[2];
  const float* W1   = (const float*)d_in[3];
  const float* b1   = (const float*)d_in[4];
  const float* W2   = (const float*)d_in[5];
  const float* b2   = (const float*)d_in[6];
  const float* W3   = (const float*)d_in[7];
  const float* b3   = (const float*)d_in[8];
  const float* mins = (const float*)d_in[9];
  const float* maxs = (const float*)d_in[10];
  float* out = (float*)d_out;
  const int N = in_sizes[0] / 3;

  char* ws = (char*)d_ws;
  int* cursors = (int*)ws;                                        // [0,32)
  f32x4* xperm = (f32x4*)(ws + 256);                              // 8 x SEGCAP x 16B
  __bf16* Wt1  = (__bf16*)(ws + 256 + (size_t)16 * SEGCAP * NMODEL);
  __bf16* Wt2  = Wt1 + NMODEL * HDIM * HDIM;

  hipMemsetAsync(cursors, 0, NMODEL * sizeof(int), stream);
  const int sb = (N + 1023) >> 10;
  srn_prep_scatter<<<dim3(64 + sb), dim3(256), 0, stream>>>(
      W1, W2, x, mins, maxs, Wt1, Wt2, cursors, xperm, N);
  srn_main<<<dim3(TILES_X, NMODEL), dim3(256), 0, stream>>>(
      W0, b0, b1, b2, W3, b3, Wt1, Wt2, cursors, xperm, out, N);
}